// Round 13
// baseline (479.571 us; speedup 1.0000x reference)
//
#include <hip/hip_runtime.h>
#include <hip/hip_bf16.h>
#include <math.h>

// MessagePassingLayer on MI355X — round 22.
// r21 post-mortem: edge occupancy lift was null (158->164, FETCH/WRITE up:
// more blocks thrash L2). Key counter: WRITE 125-150MB vs 25.6MB ideal upd
// traffic = 5x atomic write-amplification (random dst -> partial lines
// migrate across 8 XCD L2s). This round: counting-sort edges by dst-bucket
// (dst>>6; hist + 1-block scan + scatter, ~10us, +1.6MB ws runtime-guarded)
// and process edges via perm[] with a bijective XCD-chunk swizzle so each
// bucket's blocks run on ONE XCD. Atomics localize to 16KB upd windows
// (written once); DstCat gathers hit a 32KB L2-resident window.
// edge body otherwise r12 at (256,6). node=r17, gemm_out=r18, prep same.

typedef __bf16 bf16x8 __attribute__((ext_vector_type(8)));
typedef __bf16 bf16x2 __attribute__((ext_vector_type(2)));
typedef float floatx4 __attribute__((ext_vector_type(4)));

#define LN_EPS 1e-5f

__device__ __forceinline__ unsigned short f2bf(float x) {
  unsigned int u = __float_as_uint(x);
  u = u + 0x7fffu + ((u >> 16) & 1u);
  return (unsigned short)(u >> 16);
}

// packed pair -> one v_cvt_pk_bf16_f32 (RNE): lo in [15:0], hi in [31:16]
__device__ __forceinline__ unsigned int pkbf(float lo, float hi) {
  bf16x2 v;
  v.x = (__bf16)lo;
  v.y = (__bf16)hi;
  return __builtin_bit_cast(unsigned int, v);
}

__device__ __forceinline__ unsigned short f2bfh(float x) {
  __bf16 h = (__bf16)x;
  return __builtin_bit_cast(unsigned short, h);
}

__device__ __forceinline__ float bf2f(unsigned short s) {
  return __uint_as_float(((unsigned int)s) << 16);
}

__device__ __forceinline__ float geluf(float x) {
  float t = x * x;
  float u = x * (2.3022080f + 0.1029434f * t);
  float e = __builtin_amdgcn_exp2f(-u);
  return x * __builtin_amdgcn_rcpf(1.0f + e);
}

__device__ __forceinline__ float sigmoidf_fast(float x) {
  float e = __builtin_amdgcn_exp2f(-1.44269504f * x);
  return __builtin_amdgcn_rcpf(1.0f + e);
}

// ---------------------------------------------------------------------------
// prep: 9 [128,128] fp32 weights -> bf16 [n][k] (transposed). 36 blocks.
// ---------------------------------------------------------------------------
__global__ __launch_bounds__(256) void prep_weights(
    const float* w0, const float* w1, const float* w2, const float* w3,
    const float* w4, const float* w5, const float* w6, const float* w7,
    const float* w8, unsigned short* out) {
  const float* srcs[9] = {w0, w1, w2, w3, w4, w5, w6, w7, w8};
  int m = blockIdx.x >> 2, c = blockIdx.x & 3;
  const float* src = srcs[m] + c * 32 * 128;
  __shared__ unsigned short sT[128][35];
  int tid = threadIdx.x;

  for (int it = 0; it < 4; ++it) {
    int f4 = tid + it * 256;
    float4 v = ((const float4*)src)[f4];
    int krel = f4 >> 5;
    int n0 = (f4 & 31) * 4;
    sT[n0 + 0][krel] = f2bf(v.x);
    sT[n0 + 1][krel] = f2bf(v.y);
    sT[n0 + 2][krel] = f2bf(v.z);
    sT[n0 + 3][krel] = f2bf(v.w);
  }
  __syncthreads();
  unsigned short* dst = out + m * 16384 + c * 32;
  for (int it = 0; it < 2; ++it) {
    int ch = tid + it * 256;
    int n = ch >> 2, kc = (ch & 3) * 8;
    unsigned short tmp[8];
    for (int j = 0; j < 8; ++j) tmp[j] = sT[n][kc + j];
    *(int4*)(dst + n * 128 + kc) = *(const int4*)tmp;
  }
}

#define LDB(pB, B)                                              \
  do {                                                          \
    const unsigned short* _p = (pB);                            \
    for (int kb = 0; kb < 4; ++kb) {                            \
      B[0][kb] = *(const bf16x8*)(_p + kb * 32);                \
      B[1][kb] = *(const bf16x8*)(_p + 2048 + kb * 32);         \
    }                                                           \
  } while (0)

// ---------------------------------------------------------------------------
// edge bucket sort by dst>>6: histogram / scan / scatter
// ---------------------------------------------------------------------------
__global__ __launch_bounds__(256) void ehist(
    const int* __restrict__ edge_dst, int* __restrict__ hist, int E) {
  int i = blockIdx.x * 256 + threadIdx.x;
  if (i < E) atomicAdd(&hist[edge_dst[i] >> 6], 1);
}

__global__ __launch_bounds__(256) void escan(
    const int* __restrict__ hist, int* __restrict__ offs, int nb) {
  __shared__ int tmp[2048];
  int tid = threadIdx.x;
  for (int i = tid; i < 2048; i += 256) tmp[i] = (i < nb) ? hist[i] : 0;
  __syncthreads();
  for (int d = 1; d < 2048; d <<= 1) {
    int vals[8];
    for (int j = 0; j < 8; ++j) {
      int i = tid + j * 256;
      vals[j] = (i >= d) ? tmp[i - d] : 0;
    }
    __syncthreads();
    for (int j = 0; j < 8; ++j) tmp[tid + j * 256] += vals[j];
    __syncthreads();
  }
  // exclusive = inclusive - self
  for (int i = tid; i < 2048; i += 256)
    offs[i] = tmp[i] - ((i < nb) ? hist[i] : 0);
}

__global__ __launch_bounds__(256) void escatter(
    const int* __restrict__ edge_dst, int* __restrict__ offs,
    int* __restrict__ perm, int E) {
  int i = blockIdx.x * 256 + threadIdx.x;
  if (i < E) {
    int pos = atomicAdd(&offs[edge_dst[i] >> 6], 1);
    perm[pos] = i;
  }
}

// ---------------------------------------------------------------------------
// node_fused (512 thr, 8 waves, 16 cols/wave): r17 winner, unchanged.
// ---------------------------------------------------------------------------
__global__ __launch_bounds__(512, 8) void node_fused(
    const float* __restrict__ feat, const unsigned short* __restrict__ wT,
    const float* __restrict__ b_src, const float* __restrict__ b_dst,
    const float* __restrict__ b1, const float* __restrict__ bg1,
    unsigned short* __restrict__ SrcCat, unsigned short* __restrict__ DstCat,
    unsigned short* __restrict__ upd, int M) {
  __shared__ __align__(16) unsigned short sF[64][136];
  __shared__ __align__(16) unsigned short sT[64][136];
  int tid = threadIdx.x;
  int r0 = blockIdx.x * 64;
  int y = blockIdx.y;

  if (y == 0) {
    int4 z = {0, 0, 0, 0};
    int4* p = (int4*)(upd + (long long)r0 * 128);
    for (int it = 0; it < 2; ++it) {
      int idx = tid + it * 512;
      if (r0 + (idx >> 4) < M) p[idx] = z;
    }
  }

  {
    int r = tid >> 3, seg = tid & 7;
    int row = r0 + r;
    const float* src = feat + (long long)row * 128 + seg * 16;
    if (row < M) {
      float4 f0 = *(const float4*)(src);
      float4 f1 = *(const float4*)(src + 4);
      float4 f2 = *(const float4*)(src + 8);
      float4 f3 = *(const float4*)(src + 12);
      unsigned int t0[4] = {pkbf(f0.x, f0.y), pkbf(f0.z, f0.w),
                            pkbf(f1.x, f1.y), pkbf(f1.z, f1.w)};
      unsigned int t1[4] = {pkbf(f2.x, f2.y), pkbf(f2.z, f2.w),
                            pkbf(f3.x, f3.y), pkbf(f3.z, f3.w)};
      *(int4*)&sF[r][seg * 16] = *(const int4*)t0;
      *(int4*)&sF[r][seg * 16 + 8] = *(const int4*)t1;
    } else {
      int4 z = {0, 0, 0, 0};
      *(int4*)&sF[r][seg * 16] = z;
      *(int4*)&sF[r][seg * 16 + 8] = z;
    }
  }
  __syncthreads();  // B1

  int w = tid >> 6;
  int lane = tid & 63, lr = lane & 15, q = lane >> 4;
  int c0 = 16 * w + lr;
  const unsigned short* pB = wT + c0 * 128 + q * 8;

  const unsigned short* wH = pB + (y ? 1 : 0) * 16384;
  const unsigned short* wA = pB + (y ? 3 : 2) * 16384;
  const unsigned short* wG = pB + (y ? 7 : 6) * 16384;
  unsigned short* Cat = y ? DstCat : SrcCat;
  float hb = y ? b_dst[c0] : b_src[c0];
  float ab = y ? 0.f : b1[c0];
  float gb = y ? 0.f : bg1[c0];

  bf16x8 B[4];
  floatx4 acc[4];

  auto ldb = [&](const unsigned short* p) {
#pragma unroll
    for (int kb = 0; kb < 4; ++kb) B[kb] = *(const bf16x8*)(p + kb * 32);
  };
  auto zacc = [&]() {
#pragma unroll
    for (int mb = 0; mb < 4; ++mb) acc[mb] = (floatx4){0.f, 0.f, 0.f, 0.f};
  };
  auto pass = [&](const unsigned short (*Ab)[136]) {
#pragma unroll
    for (int kb = 0; kb < 4; ++kb) {
      int k = kb * 32 + q * 8;
#pragma unroll
      for (int mb = 0; mb < 4; ++mb) {
        bf16x8 a = *(const bf16x8*)&Ab[16 * mb + lr][k];
        acc[mb] = __builtin_amdgcn_mfma_f32_16x16x32_bf16(a, B[kb], acc[mb], 0, 0, 0);
      }
    }
  };
  auto stage = [&](unsigned short (*S)[136], float bv) {
#pragma unroll
    for (int mb = 0; mb < 4; ++mb)
#pragma unroll
      for (int i = 0; i < 4; ++i)
        S[16 * mb + 4 * q + i][c0] = f2bfh(acc[mb][i] + bv);
  };

  ldb(wH); zacc(); pass(sF); stage(sT, hb);
  __syncthreads();  // B2

  ldb(wA); zacc(); pass(sT); stage(sF, ab);
  ldb(wG); zacc(); pass(sT);
  __syncthreads();  // B3
  stage(sT, gb);
  __syncthreads();  // B4

  for (int it = 0; it < 4; ++it) {
    int idx = tid + it * 512;
    int row = idx >> 5, c = idx & 31;
    if (r0 + row < M) {
      const void* src = (c < 16) ? (const void*)&sF[row][c * 8]
                                 : (const void*)&sT[row][(c - 16) * 8];
      *(int4*)(Cat + (long long)(r0 + row) * 256 + c * 8) = *(const int4*)src;
    }
  }
}

// ---------------------------------------------------------------------------
// out GEMM (512 thr, 8 waves, 16 cols/wave): r18, unchanged.
// ---------------------------------------------------------------------------
__global__ __launch_bounds__(512, 8) void gemm_out(
    const unsigned short* __restrict__ A, const unsigned short* __restrict__ Bt,
    const float* __restrict__ bias, float* __restrict__ C, int M) {
  __shared__ __align__(16) char smem[64 * 130 * 4];
  unsigned short (*sA)[136] = (unsigned short(*)[136])smem;
  float (*sO)[130] = (float(*)[130])smem;
  int tid = threadIdx.x;
  int r0 = blockIdx.x * 64;

  for (int it = 0; it < 2; ++it) {
    int idx = tid + it * 512;
    int row = idx >> 4, c = idx & 15;
    int4 v = {0, 0, 0, 0};
    if (r0 + row < M) v = ((const int4*)(A + (long long)(r0 + row) * 128))[c];
    *(int4*)&sA[row][c * 8] = v;
  }
  __syncthreads();

  int w = tid >> 6, lane = tid & 63, lr = lane & 15, q = lane >> 4;
  int c0 = 16 * w + lr;
  const unsigned short* pB = Bt + c0 * 128 + q * 8;

  bf16x8 B[4];
#pragma unroll
  for (int kb = 0; kb < 4; ++kb) B[kb] = *(const bf16x8*)(pB + kb * 32);
  floatx4 acc[4];
#pragma unroll
  for (int mb = 0; mb < 4; ++mb) acc[mb] = (floatx4){0.f, 0.f, 0.f, 0.f};
#pragma unroll
  for (int kb = 0; kb < 4; ++kb) {
    int k = kb * 32 + q * 8;
#pragma unroll
    for (int mb = 0; mb < 4; ++mb) {
      bf16x8 a = *(const bf16x8*)&sA[16 * mb + lr][k];
      acc[mb] = __builtin_amdgcn_mfma_f32_16x16x32_bf16(a, B[kb], acc[mb], 0, 0, 0);
    }
  }
  __syncthreads();

  float bv = bias[c0];
#pragma unroll
  for (int mb = 0; mb < 4; ++mb)
#pragma unroll
    for (int i = 0; i < 4; ++i)
      sO[16 * mb + 4 * q + i][c0] = acc[mb][i] + bv;
  __syncthreads();

  for (int it = 0; it < 4; ++it) {
    int idx = tid + it * 512;
    int row = idx >> 5, c = idx & 31;
    if (r0 + row < M)
      *(float4*)(C + (long long)(r0 + row) * 128 + c * 4) = *(const float4*)&sO[row][c * 4];
  }
}

// ---------------------------------------------------------------------------
// edge_fused: 64 edges/block, 256 thr (r12 body at (256,6)) +
// dst-sorted perm indirection + bijective XCD-chunk swizzle.
// ---------------------------------------------------------------------------
__global__ __launch_bounds__(256, 6) void edge_fused(
    const unsigned short* __restrict__ SrcCat, const unsigned short* __restrict__ DstCat,
    const int* __restrict__ edge_src, const int* __restrict__ edge_dst,
    const int* __restrict__ perm,
    const unsigned short* __restrict__ wT,
    const float* __restrict__ b2, const float* __restrict__ b3,
    const float* __restrict__ ln_g, const float* __restrict__ ln_b,
    const float* __restrict__ Wg2, const float* __restrict__ bg2,
    unsigned short* __restrict__ upd, int E) {
  __shared__ __align__(16) unsigned short sH[64][136];  // h1 then h2 (in place)
  __shared__ int sDst[64];
  __shared__ float sGate[64];
  __shared__ float sR1[4][64];
  __shared__ float sR2[4][64];
  __shared__ float sM[64];
  __shared__ float sRS[64];
  // total: 20480 B

  int tid = threadIdx.x;
  // bijective XCD-chunk swizzle: workgroups dispatched round-robin over 8
  // XCDs get contiguous work chunks per XCD -> bucket-sharing blocks stay
  // on one L2.
  int nwg = gridDim.x;
  int bq = nwg >> 3, br = nwg & 7;
  int xcd = blockIdx.x & 7, j = blockIdx.x >> 3;
  int wk = (xcd < br) ? xcd * (bq + 1) + j : br * (bq + 1) + (xcd - br) * bq + j;
  int e0 = wk * 64;

  {  // gather + h1 + gate
    int r = tid >> 2, seg = tid & 3;
    int e = e0 + r;
    int ee = (e < E) ? e : (E - 1);
    if (perm) ee = perm[ee];
    int es = edge_src[ee], ed = edge_dst[ee];
    if (seg == 0) sDst[r] = (e < E) ? ed : -1;
    const unsigned short* ps = SrcCat + (long long)es * 256 + seg * 32;
    const unsigned short* pd = DstCat + (long long)ed * 256 + seg * 32;

    int4 sa[4], sb[4], ga[4], gb[4];
    for (int u = 0; u < 4; ++u) {
      sa[u] = ((const int4*)ps)[u];
      sb[u] = ((const int4*)pd)[u];
      ga[u] = ((const int4*)(ps + 128))[u];
      gb[u] = ((const int4*)(pd + 128))[u];
    }
    for (int u = 0; u < 4; ++u) {
      const unsigned short* av = (const unsigned short*)&sa[u];
      const unsigned short* bv = (const unsigned short*)&sb[u];
      unsigned int ov[4];
      for (int j2 = 0; j2 < 4; ++j2) {
        float g0 = geluf(bf2f(av[2 * j2])     + bf2f(bv[2 * j2]));
        float g1 = geluf(bf2f(av[2 * j2 + 1]) + bf2f(bv[2 * j2 + 1]));
        ov[j2] = pkbf(g0, g1);
      }
      *(int4*)&sH[r][seg * 32 + u * 8] = *(const int4*)ov;
    }
    float gp = 0.f;
    for (int u = 0; u < 4; ++u) {
      const unsigned short* av = (const unsigned short*)&ga[u];
      const unsigned short* bv = (const unsigned short*)&gb[u];
      float4 w0 = *(const float4*)(Wg2 + seg * 32 + u * 8);
      float4 w1 = *(const float4*)(Wg2 + seg * 32 + u * 8 + 4);
      gp += geluf(bf2f(av[0]) + bf2f(bv[0])) * w0.x;
      gp += geluf(bf2f(av[1]) + bf2f(bv[1])) * w0.y;
      gp += geluf(bf2f(av[2]) + bf2f(bv[2])) * w0.z;
      gp += geluf(bf2f(av[3]) + bf2f(bv[3])) * w0.w;
      gp += geluf(bf2f(av[4]) + bf2f(bv[4])) * w1.x;
      gp += geluf(bf2f(av[5]) + bf2f(bv[5])) * w1.y;
      gp += geluf(bf2f(av[6]) + bf2f(bv[6])) * w1.z;
      gp += geluf(bf2f(av[7]) + bf2f(bv[7])) * w1.w;
    }
    gp += __shfl_xor(gp, 1);
    gp += __shfl_xor(gp, 2);
    if (seg == 0) sGate[r] = sigmoidf_fast(gp + bg2[0]);
  }
  __syncthreads();  // B1

  int w = tid >> 6, lane = tid & 63, lr = lane & 15, q = lane >> 4;
  int c0 = 32 * w + lr, c1 = 32 * w + 16 + lr;
  const unsigned short* pB = wT + c0 * 128 + q * 8;

  bf16x8 B[2][4];
  floatx4 acc[4][2];
  auto zacc = [&]() {
    for (int mb = 0; mb < 4; ++mb)
      for (int nb = 0; nb < 2; ++nb) acc[mb][nb] = (floatx4){0.f, 0.f, 0.f, 0.f};
  };
  auto pass = [&](const unsigned short (*Ab)[136]) {
    for (int kb = 0; kb < 4; ++kb) {
      int k = kb * 32 + q * 8;
      for (int mb = 0; mb < 4; ++mb) {
        bf16x8 a = *(const bf16x8*)&Ab[16 * mb + lr][k];
        acc[mb][0] = __builtin_amdgcn_mfma_f32_16x16x32_bf16(a, B[0][kb], acc[mb][0], 0, 0, 0);
        acc[mb][1] = __builtin_amdgcn_mfma_f32_16x16x32_bf16(a, B[1][kb], acc[mb][1], 0, 0, 0);
      }
    }
  };

  // ---- stage 2: h2 = gelu(h1@W2 + b2), in place ----
  LDB(pB + 4 * 16384, B);
  zacc();
  pass(sH);
  __syncthreads();  // B2
  {
    float bv0 = b2[c0], bv1 = b2[c1];
    for (int mb = 0; mb < 4; ++mb)
      for (int i = 0; i < 4; ++i) {
        int r = 16 * mb + 4 * q + i;
        unsigned int u = pkbf(geluf(acc[mb][0][i] + bv0), geluf(acc[mb][1][i] + bv1));
        sH[r][c0] = (unsigned short)u;
        sH[r][c1] = (unsigned short)(u >> 16);
      }
  }
  __syncthreads();  // B3

  // ---- stage 3 + LN partials ----
  LDB(pB + 5 * 16384, B);
  zacc();
  pass(sH);
  {
    float bv0 = b3[c0], bv1 = b3[c1];
    for (int mb = 0; mb < 4; ++mb)
      for (int i = 0; i < 4; ++i) {
        float x0 = acc[mb][0][i] + bv0;
        float x1 = acc[mb][1][i] + bv1;
        acc[mb][0][i] = x0; acc[mb][1][i] = x1;
        float s = x0 + x1, s2 = x0 * x0 + x1 * x1;
        s += __shfl_xor(s, 1); s += __shfl_xor(s, 2);
        s += __shfl_xor(s, 4); s += __shfl_xor(s, 8);
        s2 += __shfl_xor(s2, 1); s2 += __shfl_xor(s2, 2);
        s2 += __shfl_xor(s2, 4); s2 += __shfl_xor(s2, 8);
        if (lr == 0) { sR1[w][16 * mb + 4 * q + i] = s; sR2[w][16 * mb + 4 * q + i] = s2; }
      }
  }
  __syncthreads();  // B4
  if (tid < 64) {
    float s = sR1[0][tid] + sR1[1][tid] + sR1[2][tid] + sR1[3][tid];
    float s2 = sR2[0][tid] + sR2[1][tid] + sR2[2][tid] + sR2[3][tid];
    float m = s * (1.f / 128.f);
    float v = s2 * (1.f / 128.f) - m * m;
    sM[tid] = m;
    sRS[tid] = rsqrtf(v + LN_EPS);
  }
  __syncthreads();  // B5

  {
    float lg0 = ln_g[c0], lg1 = ln_g[c1];
    float lb0 = ln_b[c0], lb1 = ln_b[c1];
    for (int mb = 0; mb < 4; ++mb)
      for (int i = 0; i < 4; ++i) {
        int r = 16 * mb + 4 * q + i;
        int dst = sDst[r];
        float m = sM[r], rs = sRS[r], gt = sGate[r];
        float v0 = ((acc[mb][0][i] - m) * rs * lg0 + lb0) * gt;
        float v1 = ((acc[mb][1][i] - m) * rs * lg1 + lb1) * gt;
        float o0 = __shfl_xor(v0, 1);
        float o1 = __shfl_xor(v1, 1);
        if (dst >= 0) {
          unsigned int pk;
          int colb;
          if ((lr & 1) == 0) {
            pk = pkbf(v0, o0);
            colb = c0;
          } else {
            pk = pkbf(o1, v1);
            colb = c0 + 15;
          }
          unsigned short* addr = upd + (long long)dst * 128 + colb;
          asm volatile("global_atomic_pk_add_bf16 %0, %1, off"
                       :: "v"(addr), "v"(pk) : "memory");
        }
      }
  }
}

// ---------------------------------------------------------------------------
extern "C" void kernel_launch(void* const* d_in, const int* in_sizes, int n_in,
                              void* d_out, int out_size, void* d_ws, size_t ws_size,
                              hipStream_t stream) {
  const float* feat   = (const float*)d_in[0];
  const int* edge_src = (const int*)d_in[1];
  const int* edge_dst = (const int*)d_in[2];
  const float* W_src = (const float*)d_in[3];  const float* b_src = (const float*)d_in[4];
  const float* W_dst = (const float*)d_in[5];  const float* b_dst = (const float*)d_in[6];
  const float* W1a = (const float*)d_in[7];    const float* W1b = (const float*)d_in[8];
  const float* b1  = (const float*)d_in[9];
  const float* W2  = (const float*)d_in[10];   const float* b2  = (const float*)d_in[11];
  const float* W3  = (const float*)d_in[12];   const float* b3  = (const float*)d_in[13];
  const float* ln_g = (const float*)d_in[14];  const float* ln_b = (const float*)d_in[15];
  const float* Wg1a = (const float*)d_in[16];  const float* Wg1b = (const float*)d_in[17];
  const float* bg1  = (const float*)d_in[18];
  const float* Wg2  = (const float*)d_in[19];  const float* bg2 = (const float*)d_in[20];
  const float* W_out = (const float*)d_in[21]; const float* b_out = (const float*)d_in[22];

  int N = in_sizes[0] / 128;   // 100000
  int E = in_sizes[1];         // 400000

  // ws: [wT 288KB][SrcCat N*256 bf16][DstCat N*256 bf16][upd N*128 bf16]
  //     [perm E int][hist 2048 int][offs 2048 int]
  char* ws = (char*)d_ws;
  unsigned short* wT = (unsigned short*)ws;
  size_t off = 9 * 16384 * sizeof(unsigned short);
  unsigned short* SrcCat = (unsigned short*)(ws + off);
  off += (size_t)N * 256 * sizeof(unsigned short);
  unsigned short* DstCat = (unsigned short*)(ws + off);
  off += (size_t)N * 256 * sizeof(unsigned short);
  unsigned short* upd = (unsigned short*)(ws + off);
  off += (size_t)N * 128 * sizeof(unsigned short);
  int* perm = (int*)(ws + off);
  size_t off_perm_end = off + (size_t)E * sizeof(int);
  int* hist = (int*)(ws + off_perm_end);
  int* offs = hist + 2048;
  size_t need = off_perm_end + 2 * 2048 * sizeof(int);
  bool use_sort = (ws_size >= need);

  prep_weights<<<36, 256, 0, stream>>>(W_src, W_dst, W1a, W1b, W2, W3, Wg1a, Wg1b,
                                       W_out, wT);
  int mtiles = (N + 63) / 64;
  node_fused<<<dim3(mtiles, 2), 512, 0, stream>>>(feat, wT, b_src, b_dst, b1, bg1,
                                                  SrcCat, DstCat, upd, N);
  if (use_sort) {
    int nb = (N + 63) / 64;   // dst>>6 buckets
    hipMemsetAsync(hist, 0, 2048 * sizeof(int), stream);
    ehist<<<(E + 255) / 256, 256, 0, stream>>>(edge_dst, hist, E);
    escan<<<1, 256, 0, stream>>>(hist, offs, nb);
    escatter<<<(E + 255) / 256, 256, 0, stream>>>(edge_dst, offs, perm, E);
  }
  edge_fused<<<(E + 63) / 64, 256, 0, stream>>>(SrcCat, DstCat, edge_src, edge_dst,
                                                use_sort ? perm : nullptr,
                                                wT, b2, b3, ln_g, ln_b, Wg2, bg2,
                                                upd, E);
  gemm_out<<<mtiles, 512, 0, stream>>>(upd, wT + 8 * 16384, b_out, (float*)d_out, N);
}

// Round 15
// 349.647 us; speedup vs baseline: 1.3716x; 1.3716x over previous
//
#include <hip/hip_runtime.h>
#include <hip/hip_bf16.h>
#include <math.h>

// MessagePassingLayer on MI355X — round 24 (r23 resubmit; container infra
// failure, no kernel verdict — third such failure, rounds 2/11/14; all
// components individually harness-proven across multiple passing runs).
// Config: node_fused r17 (512thr/8wave/16col, 100% occ), gemm_out r18
// (same shape), edge_fused r12 body at (256,6), prep unchanged.
// Measured 350.4 (r17) / 352.1 (r18) across two containers.
// r22 post-mortem stands: edge is issue/latency-bound (traffic -26% ->
// time flat; occ +20pt -> time flat/worse), sort pipeline stripped.

typedef __bf16 bf16x8 __attribute__((ext_vector_type(8)));
typedef __bf16 bf16x2 __attribute__((ext_vector_type(2)));
typedef float floatx4 __attribute__((ext_vector_type(4)));

#define LN_EPS 1e-5f

__device__ __forceinline__ unsigned short f2bf(float x) {
  unsigned int u = __float_as_uint(x);
  u = u + 0x7fffu + ((u >> 16) & 1u);
  return (unsigned short)(u >> 16);
}

// packed pair -> one v_cvt_pk_bf16_f32 (RNE): lo in [15:0], hi in [31:16]
__device__ __forceinline__ unsigned int pkbf(float lo, float hi) {
  bf16x2 v;
  v.x = (__bf16)lo;
  v.y = (__bf16)hi;
  return __builtin_bit_cast(unsigned int, v);
}

__device__ __forceinline__ unsigned short f2bfh(float x) {
  __bf16 h = (__bf16)x;
  return __builtin_bit_cast(unsigned short, h);
}

__device__ __forceinline__ float bf2f(unsigned short s) {
  return __uint_as_float(((unsigned int)s) << 16);
}

__device__ __forceinline__ float geluf(float x) {
  float t = x * x;
  float u = x * (2.3022080f + 0.1029434f * t);
  float e = __builtin_amdgcn_exp2f(-u);
  return x * __builtin_amdgcn_rcpf(1.0f + e);
}

__device__ __forceinline__ float sigmoidf_fast(float x) {
  float e = __builtin_amdgcn_exp2f(-1.44269504f * x);
  return __builtin_amdgcn_rcpf(1.0f + e);
}

// ---------------------------------------------------------------------------
// prep: 9 [128,128] fp32 weights -> bf16 [n][k] (transposed). 36 blocks.
// slots: 0 WsrcT 1 WdstT 2 W1aT 3 W1bT 4 W2T 5 W3T 6 Wg1aT 7 Wg1bT 8 WoutT
// ---------------------------------------------------------------------------
__global__ __launch_bounds__(256) void prep_weights(
    const float* w0, const float* w1, const float* w2, const float* w3,
    const float* w4, const float* w5, const float* w6, const float* w7,
    const float* w8, unsigned short* out) {
  const float* srcs[9] = {w0, w1, w2, w3, w4, w5, w6, w7, w8};
  int m = blockIdx.x >> 2, c = blockIdx.x & 3;
  const float* src = srcs[m] + c * 32 * 128;
  __shared__ unsigned short sT[128][35];
  int tid = threadIdx.x;

  for (int it = 0; it < 4; ++it) {
    int f4 = tid + it * 256;
    float4 v = ((const float4*)src)[f4];
    int krel = f4 >> 5;
    int n0 = (f4 & 31) * 4;
    sT[n0 + 0][krel] = f2bf(v.x);
    sT[n0 + 1][krel] = f2bf(v.y);
    sT[n0 + 2][krel] = f2bf(v.z);
    sT[n0 + 3][krel] = f2bf(v.w);
  }
  __syncthreads();
  unsigned short* dst = out + m * 16384 + c * 32;
  for (int it = 0; it < 2; ++it) {
    int ch = tid + it * 256;
    int n = ch >> 2, kc = (ch & 3) * 8;
    unsigned short tmp[8];
    for (int j = 0; j < 8; ++j) tmp[j] = sT[n][kc + j];
    *(int4*)(dst + n * 128 + kc) = *(const int4*)tmp;
  }
}

#define LDB(pB, B)                                              \
  do {                                                          \
    const unsigned short* _p = (pB);                            \
    for (int kb = 0; kb < 4; ++kb) {                            \
      B[0][kb] = *(const bf16x8*)(_p + kb * 32);                \
      B[1][kb] = *(const bf16x8*)(_p + 2048 + kb * 32);         \
    }                                                           \
  } while (0)

// ---------------------------------------------------------------------------
// node_fused (512 thr, 8 waves, 16 cols/wave): blockIdx.y=0 -> SrcCat,
// y=1 -> DstCat. y==0 blocks zero their 64 rows of upd. (r17 winner)
// ---------------------------------------------------------------------------
__global__ __launch_bounds__(512, 8) void node_fused(
    const float* __restrict__ feat, const unsigned short* __restrict__ wT,
    const float* __restrict__ b_src, const float* __restrict__ b_dst,
    const float* __restrict__ b1, const float* __restrict__ bg1,
    unsigned short* __restrict__ SrcCat, unsigned short* __restrict__ DstCat,
    unsigned short* __restrict__ upd, int M) {
  __shared__ __align__(16) unsigned short sF[64][136];
  __shared__ __align__(16) unsigned short sT[64][136];
  int tid = threadIdx.x;
  int r0 = blockIdx.x * 64;
  int y = blockIdx.y;

  if (y == 0) {  // zero upd rows [r0, r0+64): 1024 int4, 2 per thread
    int4 z = {0, 0, 0, 0};
    int4* p = (int4*)(upd + (long long)r0 * 128);
    for (int it = 0; it < 2; ++it) {
      int idx = tid + it * 512;
      if (r0 + (idx >> 4) < M) p[idx] = z;
    }
  }

  {  // stage feat -> sF: each thread 16 consecutive floats (64B) -> 2 int4
    int r = tid >> 3, seg = tid & 7;
    int row = r0 + r;
    const float* src = feat + (long long)row * 128 + seg * 16;
    if (row < M) {
      float4 f0 = *(const float4*)(src);
      float4 f1 = *(const float4*)(src + 4);
      float4 f2 = *(const float4*)(src + 8);
      float4 f3 = *(const float4*)(src + 12);
      unsigned int t0[4] = {pkbf(f0.x, f0.y), pkbf(f0.z, f0.w),
                            pkbf(f1.x, f1.y), pkbf(f1.z, f1.w)};
      unsigned int t1[4] = {pkbf(f2.x, f2.y), pkbf(f2.z, f2.w),
                            pkbf(f3.x, f3.y), pkbf(f3.z, f3.w)};
      *(int4*)&sF[r][seg * 16] = *(const int4*)t0;
      *(int4*)&sF[r][seg * 16 + 8] = *(const int4*)t1;
    } else {
      int4 z = {0, 0, 0, 0};
      *(int4*)&sF[r][seg * 16] = z;
      *(int4*)&sF[r][seg * 16 + 8] = z;
    }
  }
  __syncthreads();  // B1: feat staged

  int w = tid >> 6;                       // wave 0..7
  int lane = tid & 63, lr = lane & 15, q = lane >> 4;
  int c0 = 16 * w + lr;                   // this wave's 16 output cols
  const unsigned short* pB = wT + c0 * 128 + q * 8;

  const unsigned short* wH = pB + (y ? 1 : 0) * 16384;
  const unsigned short* wA = pB + (y ? 3 : 2) * 16384;
  const unsigned short* wG = pB + (y ? 7 : 6) * 16384;
  unsigned short* Cat = y ? DstCat : SrcCat;
  float hb = y ? b_dst[c0] : b_src[c0];
  float ab = y ? 0.f : b1[c0];
  float gb = y ? 0.f : bg1[c0];

  bf16x8 B[4];
  floatx4 acc[4];

  auto ldb = [&](const unsigned short* p) {
#pragma unroll
    for (int kb = 0; kb < 4; ++kb) B[kb] = *(const bf16x8*)(p + kb * 32);
  };
  auto zacc = [&]() {
#pragma unroll
    for (int mb = 0; mb < 4; ++mb) acc[mb] = (floatx4){0.f, 0.f, 0.f, 0.f};
  };
  auto pass = [&](const unsigned short (*Ab)[136]) {
#pragma unroll
    for (int kb = 0; kb < 4; ++kb) {
      int k = kb * 32 + q * 8;
#pragma unroll
      for (int mb = 0; mb < 4; ++mb) {
        bf16x8 a = *(const bf16x8*)&Ab[16 * mb + lr][k];
        acc[mb] = __builtin_amdgcn_mfma_f32_16x16x32_bf16(a, B[kb], acc[mb], 0, 0, 0);
      }
    }
  };
  auto stage = [&](unsigned short (*S)[136], float bv) {
#pragma unroll
    for (int mb = 0; mb < 4; ++mb)
#pragma unroll
      for (int i = 0; i < 4; ++i)
        S[16 * mb + 4 * q + i][c0] = f2bfh(acc[mb][i] + bv);
  };

  // h = feat@W{src,dst} + b -> sT
  ldb(wH); zacc(); pass(sF); stage(sT, hb);
  __syncthreads();  // B2: h visible; sF dead (all feat reads done)

  // A1 = h@W1 + b1 -> sF (col-private writes into dead buffer, no barrier)
  ldb(wA); zacc(); pass(sT); stage(sF, ab);
  // P = h@Wg1 + bg1
  ldb(wG); zacc(); pass(sT);
  __syncthreads();  // B3: all sT reads drained
  stage(sT, gb);    // P -> sT
  __syncthreads();  // B4: both staged tiles visible

  // coalesced copy: 64 rows x 256 cols bf16 = 2048 int4, 4 per thread
  for (int it = 0; it < 4; ++it) {
    int idx = tid + it * 512;
    int row = idx >> 5, c = idx & 31;   // c in [0,32): col chunk of 8
    if (r0 + row < M) {
      const void* src = (c < 16) ? (const void*)&sF[row][c * 8]
                                 : (const void*)&sT[row][(c - 16) * 8];
      *(int4*)(Cat + (long long)(r0 + row) * 256 + c * 8) = *(const int4*)src;
    }
  }
}

// ---------------------------------------------------------------------------
// out GEMM (512 thr, 8 waves, 16 cols/wave): d_out = upd(bf16)@Wout + b_out.
// ---------------------------------------------------------------------------
__global__ __launch_bounds__(512, 8) void gemm_out(
    const unsigned short* __restrict__ A, const unsigned short* __restrict__ Bt,
    const float* __restrict__ bias, float* __restrict__ C, int M) {
  __shared__ __align__(16) char smem[64 * 130 * 4];  // 33280 B
  unsigned short (*sA)[136] = (unsigned short(*)[136])smem;   // staging (17 KB)
  float (*sO)[130] = (float(*)[130])smem;                     // fp32 out tile
  int tid = threadIdx.x;
  int r0 = blockIdx.x * 64;

  // stage upd tile: 64 rows x 16 int4 = 1024 int4, 2 per thread
  for (int it = 0; it < 2; ++it) {
    int idx = tid + it * 512;
    int row = idx >> 4, c = idx & 15;
    int4 v = {0, 0, 0, 0};
    if (r0 + row < M) v = ((const int4*)(A + (long long)(r0 + row) * 128))[c];
    *(int4*)&sA[row][c * 8] = v;
  }
  __syncthreads();

  int w = tid >> 6, lane = tid & 63, lr = lane & 15, q = lane >> 4;
  int c0 = 16 * w + lr;                   // this wave's 16 output cols
  const unsigned short* pB = Bt + c0 * 128 + q * 8;

  bf16x8 B[4];
#pragma unroll
  for (int kb = 0; kb < 4; ++kb) B[kb] = *(const bf16x8*)(pB + kb * 32);
  floatx4 acc[4];
#pragma unroll
  for (int mb = 0; mb < 4; ++mb) acc[mb] = (floatx4){0.f, 0.f, 0.f, 0.f};
#pragma unroll
  for (int kb = 0; kb < 4; ++kb) {
    int k = kb * 32 + q * 8;
#pragma unroll
    for (int mb = 0; mb < 4; ++mb) {
      bf16x8 a = *(const bf16x8*)&sA[16 * mb + lr][k];
      acc[mb] = __builtin_amdgcn_mfma_f32_16x16x32_bf16(a, B[kb], acc[mb], 0, 0, 0);
    }
  }
  __syncthreads();  // all sA reads done before fp32 overwrite

  float bv = bias[c0];
#pragma unroll
  for (int mb = 0; mb < 4; ++mb)
#pragma unroll
    for (int i = 0; i < 4; ++i)
      sO[16 * mb + 4 * q + i][c0] = acc[mb][i] + bv;
  __syncthreads();  // fp32 tile visible

  // coalesced: 64 rows x 128 fp32 = 2048 float4, 4 per thread
  for (int it = 0; it < 4; ++it) {
    int idx = tid + it * 512;
    int row = idx >> 5, c = idx & 31;
    if (r0 + row < M)
      *(float4*)(C + (long long)(r0 + row) * 128 + c * 4) = *(const float4*)&sO[row][c * 4];
  }
}

// ---------------------------------------------------------------------------
// edge_fused: 64 edges/block, 256 thr (r12 body at (256,6) — best measured).
// ---------------------------------------------------------------------------
__global__ __launch_bounds__(256, 6) void edge_fused(
    const unsigned short* __restrict__ SrcCat, const unsigned short* __restrict__ DstCat,
    const int* __restrict__ edge_src, const int* __restrict__ edge_dst,
    const unsigned short* __restrict__ wT,
    const float* __restrict__ b2, const float* __restrict__ b3,
    const float* __restrict__ ln_g, const float* __restrict__ ln_b,
    const float* __restrict__ Wg2, const float* __restrict__ bg2,
    unsigned short* __restrict__ upd, int E) {
  __shared__ __align__(16) unsigned short sH[64][136];  // h1 then h2 (in place)
  __shared__ int sDst[64];
  __shared__ float sGate[64];
  __shared__ float sR1[4][64];
  __shared__ float sR2[4][64];
  __shared__ float sM[64];
  __shared__ float sRS[64];
  // total: 17408 + 256 + 256 + 1024 + 1024 + 256 + 256 = 20480 B

  int tid = threadIdx.x;
  int e0 = blockIdx.x * 64;

  {  // gather + h1 + gate (partials reduced in-wave: seg quad = adjacent lanes)
    int r = tid >> 2, seg = tid & 3;
    int e = e0 + r;
    int ee = (e < E) ? e : (E - 1);
    int es = edge_src[ee], ed = edge_dst[ee];
    if (seg == 0) sDst[r] = (e < E) ? ed : -1;
    const unsigned short* ps = SrcCat + (long long)es * 256 + seg * 32;
    const unsigned short* pd = DstCat + (long long)ed * 256 + seg * 32;

    int4 sa[4], sb[4], ga[4], gb[4];
    for (int u = 0; u < 4; ++u) {
      sa[u] = ((const int4*)ps)[u];
      sb[u] = ((const int4*)pd)[u];
      ga[u] = ((const int4*)(ps + 128))[u];
      gb[u] = ((const int4*)(pd + 128))[u];
    }
    for (int u = 0; u < 4; ++u) {
      const unsigned short* av = (const unsigned short*)&sa[u];
      const unsigned short* bv = (const unsigned short*)&sb[u];
      unsigned int ov[4];
      for (int j = 0; j < 4; ++j) {
        float g0 = geluf(bf2f(av[2 * j])     + bf2f(bv[2 * j]));
        float g1 = geluf(bf2f(av[2 * j + 1]) + bf2f(bv[2 * j + 1]));
        ov[j] = pkbf(g0, g1);
      }
      *(int4*)&sH[r][seg * 32 + u * 8] = *(const int4*)ov;
    }
    float gp = 0.f;
    for (int u = 0; u < 4; ++u) {
      const unsigned short* av = (const unsigned short*)&ga[u];
      const unsigned short* bv = (const unsigned short*)&gb[u];
      float4 w0 = *(const float4*)(Wg2 + seg * 32 + u * 8);
      float4 w1 = *(const float4*)(Wg2 + seg * 32 + u * 8 + 4);
      gp += geluf(bf2f(av[0]) + bf2f(bv[0])) * w0.x;
      gp += geluf(bf2f(av[1]) + bf2f(bv[1])) * w0.y;
      gp += geluf(bf2f(av[2]) + bf2f(bv[2])) * w0.z;
      gp += geluf(bf2f(av[3]) + bf2f(bv[3])) * w0.w;
      gp += geluf(bf2f(av[4]) + bf2f(bv[4])) * w1.x;
      gp += geluf(bf2f(av[5]) + bf2f(bv[5])) * w1.y;
      gp += geluf(bf2f(av[6]) + bf2f(bv[6])) * w1.z;
      gp += geluf(bf2f(av[7]) + bf2f(bv[7])) * w1.w;
    }
    gp += __shfl_xor(gp, 1);
    gp += __shfl_xor(gp, 2);
    if (seg == 0) sGate[r] = sigmoidf_fast(gp + bg2[0]);
  }
  __syncthreads();  // B1: h1 + gate + dst staged

  int w = tid >> 6, lane = tid & 63, lr = lane & 15, q = lane >> 4;
  int c0 = 32 * w + lr, c1 = 32 * w + 16 + lr;
  const unsigned short* pB = wT + c0 * 128 + q * 8;

  bf16x8 B[2][4];
  floatx4 acc[4][2];
  auto zacc = [&]() {
    for (int mb = 0; mb < 4; ++mb)
      for (int nb = 0; nb < 2; ++nb) acc[mb][nb] = (floatx4){0.f, 0.f, 0.f, 0.f};
  };
  auto pass = [&](const unsigned short (*Ab)[136]) {
    for (int kb = 0; kb < 4; ++kb) {
      int k = kb * 32 + q * 8;
      for (int mb = 0; mb < 4; ++mb) {
        bf16x8 a = *(const bf16x8*)&Ab[16 * mb + lr][k];
        acc[mb][0] = __builtin_amdgcn_mfma_f32_16x16x32_bf16(a, B[0][kb], acc[mb][0], 0, 0, 0);
        acc[mb][1] = __builtin_amdgcn_mfma_f32_16x16x32_bf16(a, B[1][kb], acc[mb][1], 0, 0, 0);
      }
    }
  };

  // ---- stage 2: h2 = gelu(h1@W2 + b2), written back into sH in place ----
  LDB(pB + 4 * 16384, B);
  zacc();
  pass(sH);
  __syncthreads();  // B2: all h1 reads drained before overwrite
  {
    float bv0 = b2[c0], bv1 = b2[c1];
    for (int mb = 0; mb < 4; ++mb)
      for (int i = 0; i < 4; ++i) {
        int r = 16 * mb + 4 * q + i;
        unsigned int u = pkbf(geluf(acc[mb][0][i] + bv0), geluf(acc[mb][1][i] + bv1));
        sH[r][c0] = (unsigned short)u;
        sH[r][c1] = (unsigned short)(u >> 16);
      }
  }
  __syncthreads();  // B3: h2 tile visible

  // ---- stage 3 + LN partials ----
  LDB(pB + 5 * 16384, B);
  zacc();
  pass(sH);
  {
    float bv0 = b3[c0], bv1 = b3[c1];
    for (int mb = 0; mb < 4; ++mb)
      for (int i = 0; i < 4; ++i) {
        float x0 = acc[mb][0][i] + bv0;
        float x1 = acc[mb][1][i] + bv1;
        acc[mb][0][i] = x0; acc[mb][1][i] = x1;
        float s = x0 + x1, s2 = x0 * x0 + x1 * x1;
        s += __shfl_xor(s, 1); s += __shfl_xor(s, 2);
        s += __shfl_xor(s, 4); s += __shfl_xor(s, 8);
        s2 += __shfl_xor(s2, 1); s2 += __shfl_xor(s2, 2);
        s2 += __shfl_xor(s2, 4); s2 += __shfl_xor(s2, 8);
        if (lr == 0) { sR1[w][16 * mb + 4 * q + i] = s; sR2[w][16 * mb + 4 * q + i] = s2; }
      }
  }
  __syncthreads();  // B4
  if (tid < 64) {
    float s = sR1[0][tid] + sR1[1][tid] + sR1[2][tid] + sR1[3][tid];
    float s2 = sR2[0][tid] + sR2[1][tid] + sR2[2][tid] + sR2[3][tid];
    float m = s * (1.f / 128.f);
    float v = s2 * (1.f / 128.f) - m * m;
    sM[tid] = m;
    sRS[tid] = rsqrtf(v + LN_EPS);
  }
  __syncthreads();  // B5

  {
    float lg0 = ln_g[c0], lg1 = ln_g[c1];
    float lb0 = ln_b[c0], lb1 = ln_b[c1];
    for (int mb = 0; mb < 4; ++mb)
      for (int i = 0; i < 4; ++i) {
        int r = 16 * mb + 4 * q + i;
        int dst = sDst[r];
        float m = sM[r], rs = sRS[r], gt = sGate[r];
        float v0 = ((acc[mb][0][i] - m) * rs * lg0 + lb0) * gt;
        float v1 = ((acc[mb][1][i] - m) * rs * lg1 + lb1) * gt;
        float o0 = __shfl_xor(v0, 1);
        float o1 = __shfl_xor(v1, 1);
        if (dst >= 0) {
          unsigned int pk;
          int colb;
          if ((lr & 1) == 0) {
            pk = pkbf(v0, o0);
            colb = c0;
          } else {
            pk = pkbf(o1, v1);
            colb = c0 + 15;
          }
          unsigned short* addr = upd + (long long)dst * 128 + colb;
          asm volatile("global_atomic_pk_add_bf16 %0, %1, off"
                       :: "v"(addr), "v"(pk) : "memory");
        }
      }
  }
}

// ---------------------------------------------------------------------------
extern "C" void kernel_launch(void* const* d_in, const int* in_sizes, int n_in,
                              void* d_out, int out_size, void* d_ws, size_t ws_size,
                              hipStream_t stream) {
  const float* feat   = (const float*)d_in[0];
  const int* edge_src = (const int*)d_in[1];
  const int* edge_dst = (const int*)d_in[2];
  const float* W_src = (const float*)d_in[3];  const float* b_src = (const float*)d_in[4];
  const float* W_dst = (const float*)d_in[5];  const float* b_dst = (const float*)d_in[6];
  const float* W1a = (const float*)d_in[7];    const float* W1b = (const float*)d_in[8];
  const float* b1  = (const float*)d_in[9];
  const float* W2  = (const float*)d_in[10];   const float* b2  = (const float*)d_in[11];
  const float* W3  = (const float*)d_in[12];   const float* b3  = (const float*)d_in[13];
  const float* ln_g = (const float*)d_in[14];  const float* ln_b = (const float*)d_in[15];
  const float* Wg1a = (const float*)d_in[16];  const float* Wg1b = (const float*)d_in[17];
  const float* bg1  = (const float*)d_in[18];
  const float* Wg2  = (const float*)d_in[19];  const float* bg2 = (const float*)d_in[20];
  const float* W_out = (const float*)d_in[21]; const float* b_out = (const float*)d_in[22];

  int N = in_sizes[0] / 128;   // 100000
  int E = in_sizes[1];         // 400000

  // ws: [wT 288KB][SrcCat bf16 N*256][DstCat bf16 N*256][upd bf16 N*128]
  char* ws = (char*)d_ws;
  unsigned short* wT = (unsigned short*)ws;
  size_t off = 9 * 16384 * sizeof(unsigned short);
  unsigned short* SrcCat = (unsigned short*)(ws + off);
  off += (size_t)N * 256 * sizeof(unsigned short);
  unsigned short* DstCat = (unsigned short*)(ws + off);
  off += (size_t)N * 256 * sizeof(unsigned short);
  unsigned short* upd = (unsigned short*)(ws + off);

  prep_weights<<<36, 256, 0, stream>>>(W_src, W_dst, W1a, W1b, W2, W3, Wg1a, Wg1b,
                                       W_out, wT);
  int mtiles = (N + 63) / 64;
  node_fused<<<dim3(mtiles, 2), 512, 0, stream>>>(feat, wT, b_src, b_dst, b1, bg1,
                                                  SrcCat, DstCat, upd, N);
  edge_fused<<<(E + 63) / 64, 256, 0, stream>>>(SrcCat, DstCat, edge_src, edge_dst,
                                                wT, b2, b3, ln_g, ln_b, Wg2, bg2,
                                                upd, E);
  gemm_out<<<mtiles, 512, 0, stream>>>(upd, wT + 8 * 16384, b_out, (float*)d_out, N);
}